// Round 4
// baseline (4574.460 us; speedup 1.0000x reference)
//
#include <hip/hip_runtime.h>
#include <stdint.h>
#include <math.h>

// ---------------------------------------------------------------------------
// SpikeICSPBLMMinimal: 128-step scan RNN. B=512, S=128, H=192, V=256, P=64, PH=16
// Kernel 1 (fold_k): algebraic folding + f16 k-pair packing of all weights
// Kernel 2 (rnn_k):  persistent per-batch-row scan; 128 blocks x 4 rows
// Kernel 3 (dec_k):  logits = hidden @ dec_W as parallel GEMM (deferred)
//
// R1: unroll-2 on mm4 (kill spills); conflict-free partial layout.
// R2: 1024-thread blocks, split-K x4 per matmul phase + reduce sub-phase.
// R3 (this): weights are step-invariant -> preload ALL per-thread weights
// into ~180 VGPRs before the t-loop (budget: 4 waves/SIMD -> 512 VGPR/wave).
// Inner loop = LDS broadcast + v_dot2_f32_f16 + barriers only; L2 latency
// off the critical path. P1 -> waves 8-15, P5 -> waves 12-15 (were idle).
// Token-gathers (sel_tok/bind_tok) prefetched at step start.
// ---------------------------------------------------------------------------

#define S_LEN 128
#define HD    192
#define VOC   256
#define PSL   64
#define PHD   16

// ws layout (in 4-byte elements)
#define OFF_SELTOK   0         // f32 [256][64]   tok@sel_W_tok + sel_b
#define OFF_BINDTOK  16384     // f32 [256][192]  tok@bind_W1_tok + bind_b1
#define OFF_SELWP    65536     // u32 [96][64]    sel_W prev-part, f16 k-pairs
#define OFF_PB       71680     // u32 [32][192]   PV@bind_W1_patch
#define OFF_BINDWP   77824     // u32 [96][192]   bind_W1 prev-part
#define OFF_BINDW2   96256     // u32 [96][192]
#define OFF_ROUTERW  114688    // u32 [192][16]   router_W (sec rows then prev rows)
#define OFF_PS       117760    // u32 [32][192]   PV@succ_W1_patch
#define OFF_PHS      123904    // u32 [8][192]    phase_embed@succ_W1_phs
#define OFF_SUCCWS   125440    // u32 [96][192]   succ_W1 sec-part
#define OFF_SUCCW2   143872    // u32 [96][192]
#define OFF_GATEW1   162304    // u32 [192][192]  gate_W1 (succ rows then prev rows)
#define OFF_DEC      199168    // u32 [96][256]   dec_W
#define WS_TOTAL     223744

typedef _Float16 h2 __attribute__((ext_vector_type(2)));

__device__ __forceinline__ float dot2f(unsigned w, unsigned x, float c) {
  h2 hw = __builtin_bit_cast(h2, w);
  h2 hx = __builtin_bit_cast(h2, x);
#if __has_builtin(__builtin_amdgcn_fdot2)
  return __builtin_amdgcn_fdot2(hw, hx, c, false);
#else
  return c + (float)hw.x * (float)hx.x + (float)hw.y * (float)hx.y;
#endif
}

__device__ __forceinline__ unsigned pk2(float a, float b) {
  _Float16 ha = (_Float16)a, hb = (_Float16)b;           // RTN converts
  unsigned short ua = __builtin_bit_cast(unsigned short, ha);
  unsigned short ub = __builtin_bit_cast(unsigned short, hb);
  return (unsigned)ua | ((unsigned)ub << 16);
}

__device__ __forceinline__ float geluf(float x) {
  return 0.5f * x * (1.0f + erff(x * 0.70710678118654752f));  // exact erf gelu
}

// 4-row dot2 block: weights W[I0..I0+3] (registers, const idx), x rows at
// XP + r*XS in LDS (wave-uniform address -> broadcast, conflict-free).
#define DOT4S(W, I0, XP, XS, A) do {                                        \
  const unsigned* _xp = (XP);                                               \
  uint4 _x0 = *(const uint4*)(_xp);                                         \
  uint4 _x1 = *(const uint4*)(_xp + (XS));                                  \
  uint4 _x2 = *(const uint4*)(_xp + 2*(XS));                                \
  uint4 _x3 = *(const uint4*)(_xp + 3*(XS));                                \
  (A)[0]=dot2f((W)[(I0)+0],_x0.x,(A)[0]); (A)[0]=dot2f((W)[(I0)+1],_x0.y,(A)[0]); \
  (A)[0]=dot2f((W)[(I0)+2],_x0.z,(A)[0]); (A)[0]=dot2f((W)[(I0)+3],_x0.w,(A)[0]); \
  (A)[1]=dot2f((W)[(I0)+0],_x1.x,(A)[1]); (A)[1]=dot2f((W)[(I0)+1],_x1.y,(A)[1]); \
  (A)[1]=dot2f((W)[(I0)+2],_x1.z,(A)[1]); (A)[1]=dot2f((W)[(I0)+3],_x1.w,(A)[1]); \
  (A)[2]=dot2f((W)[(I0)+0],_x2.x,(A)[2]); (A)[2]=dot2f((W)[(I0)+1],_x2.y,(A)[2]); \
  (A)[2]=dot2f((W)[(I0)+2],_x2.z,(A)[2]); (A)[2]=dot2f((W)[(I0)+3],_x2.w,(A)[2]); \
  (A)[3]=dot2f((W)[(I0)+0],_x3.x,(A)[3]); (A)[3]=dot2f((W)[(I0)+1],_x3.y,(A)[3]); \
  (A)[3]=dot2f((W)[(I0)+2],_x3.z,(A)[3]); (A)[3]=dot2f((W)[(I0)+3],_x3.w,(A)[3]); \
} while (0)

// ---------------------------------------------------------------------------
// fold kernel: region-dispatch by blockIdx.x (874 blocks x 256 threads)
// ---------------------------------------------------------------------------
__global__ __launch_bounds__(256) void fold_k(
    const float* __restrict__ emb,  const float* __restrict__ selW,
    const float* __restrict__ selb, const float* __restrict__ PV,
    const float* __restrict__ bW1,  const float* __restrict__ bb1,
    const float* __restrict__ bW2,  const float* __restrict__ phE,
    const float* __restrict__ rW,   const float* __restrict__ sW1,
    const float* __restrict__ sW2,  const float* __restrict__ gW1,
    const float* __restrict__ decW, float* __restrict__ ws)
{
  unsigned* wsu = (unsigned*)ws;
  int blk = blockIdx.x, tid = threadIdx.x;

  if (blk < 64) {                       // sel_tok [256][64] f32
    int o = blk * 256 + tid; int v = o >> 6, c = o & 63;
    float a = selb[c];
    const float* er = emb + v * HD;
    for (int h = 0; h < HD; ++h) a += er[h] * selW[h * PSL + c];
    ws[OFF_SELTOK + o] = a;
  } else if (blk < 256) {               // bind_tok [256][192] f32
    int o = (blk - 64) * 256 + tid; int v = o / HD, c = o % HD;
    float a = bb1[c];
    const float* er = emb + v * HD;
    for (int h = 0; h < HD; ++h) a += er[h] * bW1[h * HD + c];
    ws[OFF_BINDTOK + o] = a;
  } else if (blk < 280) {               // PB2: PV @ bind_W1[192:384]
    int o = (blk - 256) * 256 + tid; int k2 = o / HD, c = o % HD;
    float lo = 0.f, hi = 0.f;
    const float* p0 = PV + (2 * k2) * HD; const float* p1 = p0 + HD;
    for (int h = 0; h < HD; ++h) { float wv = bW1[(HD + h) * HD + c]; lo += p0[h] * wv; hi += p1[h] * wv; }
    wsu[OFF_PB + o] = pk2(lo, hi);
  } else if (blk < 304) {               // PS2: PV @ succ_W1[192:384]
    int o = (blk - 280) * 256 + tid; int k2 = o / HD, c = o % HD;
    float lo = 0.f, hi = 0.f;
    const float* p0 = PV + (2 * k2) * HD; const float* p1 = p0 + HD;
    for (int h = 0; h < HD; ++h) { float wv = sW1[(HD + h) * HD + c]; lo += p0[h] * wv; hi += p1[h] * wv; }
    wsu[OFF_PS + o] = pk2(lo, hi);
  } else if (blk < 310) {               // PhS2: phase_embed @ succ_W1[384:576]
    int o = (blk - 304) * 256 + tid; int k2 = o / HD, c = o % HD;
    float lo = 0.f, hi = 0.f;
    const float* p0 = phE + (2 * k2) * HD; const float* p1 = p0 + HD;
    for (int h = 0; h < HD; ++h) { float wv = sW1[(2 * HD + h) * HD + c]; lo += p0[h] * wv; hi += p1[h] * wv; }
    wsu[OFF_PHS + o] = pk2(lo, hi);
  } else if (blk < 334) {               // selWp2 [96][64] from sel_W rows 192..383
    int o = (blk - 310) * 256 + tid; int k2 = o >> 6, c = o & 63;
    wsu[OFF_SELWP + o] = pk2(selW[(HD + 2 * k2) * PSL + c], selW[(HD + 2 * k2 + 1) * PSL + c]);
  } else if (blk < 406) {               // bindWp2 [96][192] from bind_W1 rows 384..575
    int o = (blk - 334) * 256 + tid; int k2 = o / HD, c = o % HD;
    wsu[OFF_BINDWP + o] = pk2(bW1[(2 * HD + 2 * k2) * HD + c], bW1[(2 * HD + 2 * k2 + 1) * HD + c]);
  } else if (blk < 478) {               // bindW2p [96][192]
    int o = (blk - 406) * 256 + tid; int k2 = o / HD, c = o % HD;
    wsu[OFF_BINDW2 + o] = pk2(bW2[(2 * k2) * HD + c], bW2[(2 * k2 + 1) * HD + c]);
  } else if (blk < 490) {               // routerW2 [192][16] (rows 0..383 paired)
    int o = (blk - 478) * 256 + tid; int k2 = o >> 4, c = o & 15;
    wsu[OFF_ROUTERW + o] = pk2(rW[(2 * k2) * PHD + c], rW[(2 * k2 + 1) * PHD + c]);
  } else if (blk < 562) {               // succWs2 [96][192] from succ_W1 rows 0..191
    int o = (blk - 490) * 256 + tid; int k2 = o / HD, c = o % HD;
    wsu[OFF_SUCCWS + o] = pk2(sW1[(2 * k2) * HD + c], sW1[(2 * k2 + 1) * HD + c]);
  } else if (blk < 634) {               // succW2p [96][192]
    int o = (blk - 562) * 256 + tid; int k2 = o / HD, c = o % HD;
    wsu[OFF_SUCCW2 + o] = pk2(sW2[(2 * k2) * HD + c], sW2[(2 * k2 + 1) * HD + c]);
  } else if (blk < 778) {               // gateW12 [192][192] (rows 0..383 paired)
    int o = (blk - 634) * 256 + tid; int k2 = o / HD, c = o % HD;
    wsu[OFF_GATEW1 + o] = pk2(gW1[(2 * k2) * HD + c], gW1[(2 * k2 + 1) * HD + c]);
  } else {                              // dec2 [96][256]
    int o = (blk - 778) * 256 + tid; int k2 = o >> 8, c = o & 255;
    wsu[OFF_DEC + o] = pk2(decW[(2 * k2) * VOC + c], decW[(2 * k2 + 1) * VOC + c]);
  }
}

// ---------------------------------------------------------------------------
// rnn kernel: 128 blocks x 1024 threads (16 waves), 4 batch rows per block.
// All per-thread weights register-resident (preloaded once). Matmul phases
// on waves 0-11 (4 k-slices x 3 col-groups); P1 on waves 8-15; P5 on 12-15.
// ---------------------------------------------------------------------------
__global__ __launch_bounds__(1024) void rnn_k(
    const int* __restrict__ ids, const float* __restrict__ ws,
    const float* __restrict__ bind_b2, const float* __restrict__ router_b,
    const float* __restrict__ succ_b1, const float* __restrict__ succ_b2,
    const float* __restrict__ gate_b1, const float* __restrict__ gate_W2,
    const float* __restrict__ gate_b2, const float* __restrict__ ln_g,
    const float* __restrict__ ln_b,
    float* __restrict__ out_hidden, float* __restrict__ out_pw,
    float* __restrict__ out_phw, float* __restrict__ out_gate)
{
  const unsigned* wsu = (const unsigned*)ws;
  const float* sel_tok  = ws + OFF_SELTOK;
  const float* bind_tok = ws + OFF_BINDTOK;
  const unsigned* selWp   = wsu + OFF_SELWP;
  const unsigned* PB      = wsu + OFF_PB;
  const unsigned* bindWp  = wsu + OFF_BINDWP;
  const unsigned* bindW2  = wsu + OFF_BINDW2;
  const unsigned* routerW = wsu + OFF_ROUTERW;
  const unsigned* PS      = wsu + OFF_PS;
  const unsigned* PhS     = wsu + OFF_PHS;
  const unsigned* succWs  = wsu + OFF_SUCCWS;
  const unsigned* succW2  = wsu + OFF_SUCCW2;
  const unsigned* gateW1  = wsu + OFF_GATEW1;

  __shared__ __align__(16) float    s_prev[4][HD];
  __shared__ __align__(16) unsigned s_prevh[4][96];
  __shared__ __align__(16) unsigned s_sech[4][96];
  __shared__ __align__(16) unsigned s_xh[4][96];
  __shared__ __align__(16) float    s_succ[4][HD];
  __shared__ __align__(16) unsigned s_succh[4][96];
  __shared__ __align__(16) unsigned s_pwh[4][32];
  __shared__ __align__(16) unsigned s_phwh[4][8];
  __shared__ __align__(16) float    s_part[3072];     // split-K partials
  __shared__ __align__(16) float    s_gpart[4][HD];
  __shared__ int s_tok[4];

  const int tid  = threadIdx.x;
  const int b0   = blockIdx.x * 4;
  const int u    = tid >> 6, lane = tid & 63;
  // matmul mapping (u<12): slice ms (0..3) x col-group -> column mc (0..191)
  const int ms   = u & 3;
  const int mc   = ((u >> 2) << 6) + lane;
  // reduce mapping (u<12): row rr (0..3) x column rc
  const int rr   = u & 3;
  const int rc   = mc;
  // P1 mapping (u>=8): slice s1 (0..7), col = lane
  const int s1   = u - 8;
  // P5 mapping (u>=12): 256 threads = slice sl5 (0..15) x col c5 (0..15)
  const int sl5  = (tid >> 4) - 48;
  const int c5   = tid & 15;

  // ---- preload all step-invariant weights into registers ----
  unsigned wP1[12];
  if (u >= 8) {
#pragma unroll
    for (int i = 0; i < 12; ++i) wP1[i] = selWp[(s1 * 12 + i) * PSL + lane];
  }
  unsigned wP5[12];
  if (u >= 12) {
#pragma unroll
    for (int i = 0; i < 12; ++i) wP5[i] = routerW[(sl5 * 12 + i) * PHD + c5];
  }
  unsigned wP3a[8], wP3b[24], wP4[24], wP7a[24], wP7p[8], wPhS[8];
  unsigned wP8[24], wP9a[24], wP9p[24];
  float f_bb2 = 0.f, f_sb1 = 0.f, f_sb2 = 0.f, f_gb1 = 0.f, f_gw2 = 0.f;
  if (u < 12) {
#pragma unroll
    for (int i = 0; i < 8; ++i)  wP3a[i] = PB[(ms * 8 + i) * HD + mc];
#pragma unroll
    for (int i = 0; i < 24; ++i) wP3b[i] = bindWp[(ms * 24 + i) * HD + mc];
#pragma unroll
    for (int i = 0; i < 24; ++i) wP4[i]  = bindW2[(ms * 24 + i) * HD + mc];
#pragma unroll
    for (int i = 0; i < 24; ++i) wP7a[i] = succWs[(ms * 24 + i) * HD + mc];
#pragma unroll
    for (int i = 0; i < 8; ++i)  wP7p[i] = PS[(ms * 8 + i) * HD + mc];
#pragma unroll
    for (int i = 0; i < 8; ++i)  wPhS[i] = PhS[i * HD + rc];
#pragma unroll
    for (int i = 0; i < 24; ++i) wP8[i]  = succW2[(ms * 24 + i) * HD + mc];
#pragma unroll
    for (int i = 0; i < 24; ++i) wP9a[i] = gateW1[(ms * 24 + i) * HD + mc];
#pragma unroll
    for (int i = 0; i < 24; ++i) wP9p[i] = gateW1[(96 + ms * 24 + i) * HD + mc];
    f_bb2 = bind_b2[rc]; f_sb1 = succ_b1[rc]; f_sb2 = succ_b2[rc];
    f_gb1 = gate_b1[rc]; f_gw2 = gate_W2[rc];
  }
  const float f_rb  = router_b[lane & 15];
  const float f_gb2 = gate_b2[0];
  const float f_lg0 = ln_g[lane], f_lg1 = ln_g[lane + 64], f_lg2 = ln_g[lane + 128];
  const float f_lb0 = ln_b[lane], f_lb1 = ln_b[lane + 64], f_lb2 = ln_b[lane + 128];

  for (int i = tid; i < 4 * HD; i += 1024) s_prev[i / HD][i % HD] = 0.f;
  for (int i = tid; i < 4 * 96; i += 1024) s_prevh[i / 96][i % 96] = 0u;
  __syncthreads();

  for (int t = 0; t < S_LEN; ++t) {
    if (tid < 4) s_tok[tid] = ids[(b0 + tid) * S_LEN + t];
    __syncthreads();

    // prefetch token-gathers (latency hides under P1)
    float g_sel  = (u < 4)  ? sel_tok[s_tok[u] * PSL + lane] : 0.f;
    float g_bind = (u < 12) ? bind_tok[s_tok[rr] * HD + rc]  : 0.f;

    // ---- P1 (waves 8..15): sel prev-part partials ----
    if (u >= 8) {
      float acc[4] = {0.f, 0.f, 0.f, 0.f};
#pragma unroll
      for (int g = 0; g < 3; ++g) DOT4S(wP1, g * 4, &s_prevh[0][s1 * 12 + g * 4], 96, acc);
#pragma unroll
      for (int r = 0; r < 4; ++r) s_part[((r << 3) | s1) * 64 + lane] = acc[r];
    }
    __syncthreads();

    // ---- P2: sel softmax (wave u = row, 64 lanes = patch slots) ----
    if (u < 4) {
      int c = lane;
      float a = g_sel;
#pragma unroll
      for (int s = 0; s < 8; ++s) a += s_part[((u << 3) | s) * 64 + c];
      float mx = a;
#pragma unroll
      for (int m = 32; m; m >>= 1) mx = fmaxf(mx, __shfl_xor(mx, m));
      float e = expf(a - mx);
      float sm = e;
#pragma unroll
      for (int m = 32; m; m >>= 1) sm += __shfl_xor(sm, m);
      float pv = e / sm;
      out_pw[(size_t)((b0 + u) * S_LEN + t) * PSL + c] = pv;
      float ov = __shfl_xor(pv, 1);
      if (!(c & 1)) s_pwh[u][c >> 1] = pk2(pv, ov);
    }
    __syncthreads();

    // ---- P3: bind1 partials ----
    if (u < 12) {
      float acc[4] = {0.f, 0.f, 0.f, 0.f};
#pragma unroll
      for (int g = 0; g < 2; ++g) DOT4S(wP3a, g * 4, &s_pwh[0][ms * 8 + g * 4], 32, acc);
#pragma unroll
      for (int g = 0; g < 6; ++g) DOT4S(wP3b, g * 4, &s_prevh[0][ms * 24 + g * 4], 96, acc);
#pragma unroll
      for (int r = 0; r < 4; ++r) s_part[((r << 2) | ms) * 192 + mc] = acc[r];
    }
    __syncthreads();
    // ---- P3b: reduce + tok table + gelu + pack ----
    if (u < 12) {
      float v = g_bind;
#pragma unroll
      for (int s = 0; s < 4; ++s) v += s_part[((rr << 2) | s) * 192 + rc];
      float g = geluf(v);
      float o = __shfl_xor(g, 1);
      if (!(lane & 1)) s_xh[rr][rc >> 1] = pk2(g, o);
    }
    __syncthreads();

    // ---- P4: bind2 partials ----
    if (u < 12) {
      float acc[4] = {0.f, 0.f, 0.f, 0.f};
#pragma unroll
      for (int g = 0; g < 6; ++g) DOT4S(wP4, g * 4, &s_xh[0][ms * 24 + g * 4], 96, acc);
#pragma unroll
      for (int r = 0; r < 4; ++r) s_part[((r << 2) | ms) * 192 + mc] = acc[r];
    }
    __syncthreads();
    // ---- P4b: reduce + bias + tanh -> sec ----
    if (u < 12) {
      float v = f_bb2;
#pragma unroll
      for (int s = 0; s < 4; ++s) v += s_part[((rr << 2) | s) * 192 + rc];
      float sv = tanhf(v);
      float o = __shfl_xor(sv, 1);
      if (!(lane & 1)) s_sech[rr][rc >> 1] = pk2(sv, o);
    }
    __syncthreads();

    // ---- P5 (waves 12..15): router partials: 16 slices x 12 kpairs x 16 cols
    if (u >= 12) {
      float acc[4] = {0.f, 0.f, 0.f, 0.f};
      if (sl5 < 8) {     // wave-uniform (waves 12,13)
#pragma unroll
        for (int g = 0; g < 3; ++g) DOT4S(wP5, g * 4, &s_sech[0][sl5 * 12 + g * 4], 96, acc);
      } else {           // waves 14,15
#pragma unroll
        for (int g = 0; g < 3; ++g) DOT4S(wP5, g * 4, &s_prevh[0][(sl5 - 8) * 12 + g * 4], 96, acc);
      }
#pragma unroll
      for (int r = 0; r < 4; ++r) s_part[r * 256 + sl5 * 16 + c5] = acc[r];
    }
    __syncthreads();

    // ---- P6: router softmax (wave u = row, lanes 0..15) ----
    if (u < 4 && lane < PHD) {
      int c = lane;
      float a = f_rb;
#pragma unroll
      for (int s = 0; s < 16; ++s) a += s_part[u * 256 + s * 16 + c];
      float mx = a;
#pragma unroll
      for (int m = 8; m; m >>= 1) mx = fmaxf(mx, __shfl_xor(mx, m));
      float e = expf(a - mx);
      float sm = e;
#pragma unroll
      for (int m = 8; m; m >>= 1) sm += __shfl_xor(sm, m);
      float ph = e / sm;
      out_phw[(size_t)((b0 + u) * S_LEN + t) * PHD + c] = ph;
      float ov = __shfl_xor(ph, 1);
      if (!(c & 1)) s_phwh[u][c >> 1] = pk2(ph, ov);
    }
    __syncthreads();

    // ---- P7: succ1 partials (sec part + patch part) ----
    if (u < 12) {
      float acc[4] = {0.f, 0.f, 0.f, 0.f};
#pragma unroll
      for (int g = 0; g < 6; ++g) DOT4S(wP7a, g * 4, &s_sech[0][ms * 24 + g * 4], 96, acc);
#pragma unroll
      for (int g = 0; g < 2; ++g) DOT4S(wP7p, g * 4, &s_pwh[0][ms * 8 + g * 4], 32, acc);
#pragma unroll
      for (int r = 0; r < 4; ++r) s_part[((r << 2) | ms) * 192 + mc] = acc[r];
    }
    __syncthreads();
    // ---- P7b: reduce + bias + phase part + gelu + pack ----
    if (u < 12) {
      float v = f_sb1;
#pragma unroll
      for (int s = 0; s < 4; ++s) v += s_part[((rr << 2) | s) * 192 + rc];
      uint4 ph0 = *(const uint4*)&s_phwh[rr][0];
      uint4 ph1 = *(const uint4*)&s_phwh[rr][4];
      v = dot2f(wPhS[0], ph0.x, v); v = dot2f(wPhS[1], ph0.y, v);
      v = dot2f(wPhS[2], ph0.z, v); v = dot2f(wPhS[3], ph0.w, v);
      v = dot2f(wPhS[4], ph1.x, v); v = dot2f(wPhS[5], ph1.y, v);
      v = dot2f(wPhS[6], ph1.z, v); v = dot2f(wPhS[7], ph1.w, v);
      float g = geluf(v);
      float o = __shfl_xor(g, 1);
      if (!(lane & 1)) s_xh[rr][rc >> 1] = pk2(g, o);
    }
    __syncthreads();

    // ---- P8: succ2 partials ----
    if (u < 12) {
      float acc[4] = {0.f, 0.f, 0.f, 0.f};
#pragma unroll
      for (int g = 0; g < 6; ++g) DOT4S(wP8, g * 4, &s_xh[0][ms * 24 + g * 4], 96, acc);
#pragma unroll
      for (int r = 0; r < 4; ++r) s_part[((r << 2) | ms) * 192 + mc] = acc[r];
    }
    __syncthreads();
    // ---- P8b: reduce + bias + tanh -> succ (f32 + packed) ----
    if (u < 12) {
      float v = f_sb2;
#pragma unroll
      for (int s = 0; s < 4; ++s) v += s_part[((rr << 2) | s) * 192 + rc];
      float sv = tanhf(v);
      s_succ[rr][rc] = sv;
      float o = __shfl_xor(sv, 1);
      if (!(lane & 1)) s_succh[rr][rc >> 1] = pk2(sv, o);
    }
    __syncthreads();

    // ---- P9: gate1 partials (succ part + prev part) ----
    if (u < 12) {
      float acc[4] = {0.f, 0.f, 0.f, 0.f};
#pragma unroll
      for (int g = 0; g < 6; ++g) DOT4S(wP9a, g * 4, &s_succh[0][ms * 24 + g * 4], 96, acc);
#pragma unroll
      for (int g = 0; g < 6; ++g) DOT4S(wP9p, g * 4, &s_prevh[0][ms * 24 + g * 4], 96, acc);
#pragma unroll
      for (int r = 0; r < 4; ++r) s_part[((r << 2) | ms) * 192 + mc] = acc[r];
    }
    __syncthreads();
    // ---- P9b: reduce + bias + gelu * gate_W2 ----
    if (u < 12) {
      float v = f_gb1;
#pragma unroll
      for (int s = 0; s < 4; ++s) v += s_part[((rr << 2) | s) * 192 + rc];
      s_gpart[rr][rc] = geluf(v) * f_gw2;
    }
    __syncthreads();

    // ---- P10: gate reduce, blend, LayerNorm (wave u = row) ----
    if (u < 4) {
      int w = u;
      float gp = s_gpart[w][lane] + s_gpart[w][lane + 64] + s_gpart[w][lane + 128];
#pragma unroll
      for (int m = 32; m; m >>= 1) gp += __shfl_xor(gp, m);
      float gv = 1.f / (1.f + expf(-(gp + f_gb2)));
      if (lane == 0) out_gate[(size_t)(b0 + w) * S_LEN + t] = gv;

      int c0 = lane, c1 = lane + 64, c2 = lane + 128;
      float h0 = gv * s_succ[w][c0] + (1.f - gv) * s_prev[w][c0];
      float h1 = gv * s_succ[w][c1] + (1.f - gv) * s_prev[w][c1];
      float h2v = gv * s_succ[w][c2] + (1.f - gv) * s_prev[w][c2];
      float sum = h0 + h1 + h2v;
#pragma unroll
      for (int m = 32; m; m >>= 1) sum += __shfl_xor(sum, m);
      float mean = sum * (1.f / 192.f);
      float d0 = h0 - mean, d1 = h1 - mean, d2 = h2v - mean;
      float vs = d0 * d0 + d1 * d1 + d2 * d2;
#pragma unroll
      for (int m = 32; m; m >>= 1) vs += __shfl_xor(vs, m);
      float rstd = rsqrtf(vs * (1.f / 192.f) + 1e-5f);
      float y0 = d0 * rstd * f_lg0 + f_lb0;
      float y1 = d1 * rstd * f_lg1 + f_lb1;
      float y2 = d2 * rstd * f_lg2 + f_lb2;
      size_t ho = (size_t)((b0 + w) * S_LEN + t) * HD;
      out_hidden[ho + c0] = y0;
      out_hidden[ho + c1] = y1;
      out_hidden[ho + c2] = y2;
      s_prev[w][c0] = y0; s_prev[w][c1] = y1; s_prev[w][c2] = y2;
      float o0 = __shfl_xor(y0, 1), o1 = __shfl_xor(y1, 1), o2 = __shfl_xor(y2, 1);
      if (!(lane & 1)) {
        s_prevh[w][c0 >> 1] = pk2(y0, o0);
        s_prevh[w][c1 >> 1] = pk2(y1, o1);
        s_prevh[w][c2 >> 1] = pk2(y2, o2);
      }
    }
    __syncthreads();
  }
}

// ---------------------------------------------------------------------------
// dec kernel: logits[65536,256] = hidden[65536,192] @ dec_W[192,256]
// 1024 blocks x 256 threads; 64 rows per block; dec_W column in registers
// ---------------------------------------------------------------------------
__global__ __launch_bounds__(256) void dec_k(
    const float* __restrict__ hid, const unsigned* __restrict__ dec2,
    float* __restrict__ logits)
{
  __shared__ __align__(16) unsigned sA[64][96];
  int tid = threadIdx.x;
  size_t r0 = (size_t)blockIdx.x * 64;

#pragma unroll
  for (int i = 0; i < 24; ++i) {
    int idx = i * 256 + tid;
    int rr = idx / 96, kk = idx % 96;
    const float2* hp = (const float2*)(hid + (r0 + rr) * HD);
    float2 v = hp[kk];
    sA[rr][kk] = pk2(v.x, v.y);
  }
  __syncthreads();

  int c = tid;
  unsigned wr[96];
#pragma unroll
  for (int k = 0; k < 96; ++k) wr[k] = dec2[k * VOC + c];

  for (int rr = 0; rr < 64; ++rr) {
    float acc = 0.f;
#pragma unroll
    for (int k4 = 0; k4 < 24; ++k4) {
      uint4 xv = *reinterpret_cast<const uint4*>(&sA[rr][k4 * 4]);
      acc = dot2f(wr[4 * k4 + 0], xv.x, acc);
      acc = dot2f(wr[4 * k4 + 1], xv.y, acc);
      acc = dot2f(wr[4 * k4 + 2], xv.z, acc);
      acc = dot2f(wr[4 * k4 + 3], xv.w, acc);
    }
    logits[(r0 + rr) * VOC + c] = acc;
  }
}

// ---------------------------------------------------------------------------
extern "C" void kernel_launch(void* const* d_in, const int* in_sizes, int n_in,
                              void* d_out, int out_size, void* d_ws, size_t ws_size,
                              hipStream_t stream)
{
  const int*   ids  = (const int*)d_in[0];
  const float* emb  = (const float*)d_in[1];
  const float* selW = (const float*)d_in[2];
  const float* selb = (const float*)d_in[3];
  const float* PV   = (const float*)d_in[4];
  const float* bW1  = (const float*)d_in[5];
  const float* bb1  = (const float*)d_in[6];
  const float* bW2  = (const float*)d_in[7];
  const float* bb2  = (const float*)d_in[8];
  const float* phE  = (const float*)d_in[9];
  const float* rW   = (const float*)d_in[10];
  const float* rb   = (const float*)d_in[11];
  const float* sW1  = (const float*)d_in[12];
  const float* sb1  = (const float*)d_in[13];
  const float* sW2  = (const float*)d_in[14];
  const float* sb2  = (const float*)d_in[15];
  const float* gW1  = (const float*)d_in[16];
  const float* gb1  = (const float*)d_in[17];
  const float* gW2  = (const float*)d_in[18];
  const float* gb2  = (const float*)d_in[19];
  const float* lng  = (const float*)d_in[20];
  const float* lnb  = (const float*)d_in[21];
  const float* decW = (const float*)d_in[22];

  float* out = (float*)d_out;
  float* o_logits = out;                         // [512][128][256]
  float* o_hidden = out + 16777216;              // [512][128][192]
  float* o_pw     = out + 29360128;              // [512][128][64]
  float* o_phw    = out + 33554432;              // [512][128][16]
  float* o_gate   = out + 34603008;              // [512][128][1]

  float* ws = (float*)d_ws;

  hipLaunchKernelGGL(fold_k, dim3(874), dim3(256), 0, stream,
                     emb, selW, selb, PV, bW1, bb1, bW2, phE, rW, sW1, sW2, gW1, decW, ws);
  hipLaunchKernelGGL(rnn_k, dim3(128), dim3(1024), 0, stream,
                     ids, ws, bb2, rb, sb1, sb2, gb1, gW2, gb2, lng, lnb,
                     o_hidden, o_pw, o_phw, o_gate);
  hipLaunchKernelGGL(dec_k, dim3(1024), dim3(256), 0, stream,
                     o_hidden, ((const unsigned*)d_ws) + OFF_DEC, o_logits);
}

// Round 5
// 1666.374 us; speedup vs baseline: 2.7452x; 2.7452x over previous
//
#include <hip/hip_runtime.h>
#include <stdint.h>
#include <math.h>

// ---------------------------------------------------------------------------
// SpikeICSPBLMMinimal: 128-step scan RNN. B=512, S=128, H=192, V=256, P=64, PH=16
// fold_k: algebraic folding + f16 k-pair packing of weights into ws
// rnn_k:  persistent scan; 256 blocks x 768 threads (12 waves) x 2 rows
// dec_k:  logits = hidden @ dec_W (deferred parallel GEMM)
//
// R1: unroll-2 (kill spills). R2: split-K + 1024 thr. R3: 2030us, latency-bound.
// R4 FAILED: launch_bounds(1024) caps VGPR at 128 -> weight arrays spilled to
//   scratch (FETCH 3.3GB of scratch re-reads). Lesson: RF/CU = 512KB < weights.
// R5 (this): three-tier weight residency at 12 waves (VGPR cap 168):
//   LDS 156KB staged once: gateW1-sec, PB, PS, selWp + activation buffers
//   Registers ~78 dw/thread: bindW2, succWs, succW2, routerW, PhS
//   L2 streams (re-laid contiguous 96B/thread, dwordx4): bindWp, gateW1-prev,
//     issued one phase early so the barrier vmcnt-drain overlaps compute.
//   2 rows/block -> 256 blocks = all 256 CUs; all 12 waves work every phase.
// ---------------------------------------------------------------------------

#define S_LEN 128
#define HD    192
#define VOC   256
#define PSL   64
#define PHD   16

// ws layout (in 4-byte elements)
#define OFF_SELTOK   0         // f32 [256][64]   tok@sel_W_tok + sel_b
#define OFF_BINDTOK  16384     // f32 [256][192]  tok@bind_W1_tok + bind_b1
#define OFF_SELWP    65536     // u32 [96][64]    sel_W prev-part, f16 k-pairs
#define OFF_PB       71680     // u32 [32][192]   PV@bind_W1_patch (row-major)
#define OFF_BINDWP   77824     // u32 RE-LAID [(ms*192+mc)*24+i]  bind_W1 prev
#define OFF_BINDW2   96256     // u32 [96][192]
#define OFF_ROUTERW  114688    // u32 [192][16]
#define OFF_PS       117760    // u32 [32][192]   PV@succ_W1_patch (row-major)
#define OFF_PHS      123904    // u32 [8][192]    phase_embed@succ_W1_phs
#define OFF_SUCCWS   125440    // u32 [96][192]
#define OFF_SUCCW2   143872    // u32 [96][192]
#define OFF_GATEW1   162304    // u32 [96][192] sec row-major + 18432 RE-LAID prev
#define OFF_DEC      199168    // u32 [96][256]
#define WS_TOTAL     223744

typedef _Float16 h2 __attribute__((ext_vector_type(2)));

__device__ __forceinline__ float dot2f(unsigned w, unsigned x, float c) {
  h2 hw = __builtin_bit_cast(h2, w);
  h2 hx = __builtin_bit_cast(h2, x);
#if __has_builtin(__builtin_amdgcn_fdot2)
  return __builtin_amdgcn_fdot2(hw, hx, c, false);
#else
  return c + (float)hw.x * (float)hx.x + (float)hw.y * (float)hx.y;
#endif
}

__device__ __forceinline__ unsigned pk2(float a, float b) {
  _Float16 ha = (_Float16)a, hb = (_Float16)b;
  unsigned short ua = __builtin_bit_cast(unsigned short, ha);
  unsigned short ub = __builtin_bit_cast(unsigned short, hb);
  return (unsigned)ua | ((unsigned)ub << 16);
}

__device__ __forceinline__ float geluf(float x) {
  return 0.5f * x * (1.0f + erff(x * 0.70710678118654752f));
}

// 24-kpair matmul, weights in registers (unsigned[24]), 2 rows
#define MM24(WREG, XSH, BASE, A0, A1) do {                                    \
  _Pragma("unroll")                                                           \
  for (int g = 0; g < 6; ++g) {                                               \
    uint4 xa = *(const uint4*)&XSH[0][(BASE) + g * 4];                        \
    uint4 xb = *(const uint4*)&XSH[1][(BASE) + g * 4];                        \
    A0 = dot2f(WREG[g*4+0], xa.x, A0); A0 = dot2f(WREG[g*4+1], xa.y, A0);     \
    A0 = dot2f(WREG[g*4+2], xa.z, A0); A0 = dot2f(WREG[g*4+3], xa.w, A0);     \
    A1 = dot2f(WREG[g*4+0], xb.x, A1); A1 = dot2f(WREG[g*4+1], xb.y, A1);     \
    A1 = dot2f(WREG[g*4+2], xb.z, A1); A1 = dot2f(WREG[g*4+3], xb.w, A1);     \
  }                                                                           \
} while (0)

// 24-kpair matmul, weights in streamed uint4[6]
#define MM24ST(ST, XSH, BASE, A0, A1) do {                                    \
  _Pragma("unroll")                                                           \
  for (int g = 0; g < 6; ++g) {                                               \
    uint4 xa = *(const uint4*)&XSH[0][(BASE) + g * 4];                        \
    uint4 xb = *(const uint4*)&XSH[1][(BASE) + g * 4];                        \
    A0 = dot2f(ST[g].x, xa.x, A0); A0 = dot2f(ST[g].y, xa.y, A0);             \
    A0 = dot2f(ST[g].z, xa.z, A0); A0 = dot2f(ST[g].w, xa.w, A0);             \
    A1 = dot2f(ST[g].x, xb.x, A1); A1 = dot2f(ST[g].y, xb.y, A1);             \
    A1 = dot2f(ST[g].z, xb.z, A1); A1 = dot2f(ST[g].w, xb.w, A1);             \
  }                                                                           \
} while (0)

// 8-kpair matmul, weights in LDS at stride LS
#define MM8L(LP, LS, XSH, BASE, A0, A1) do {                                  \
  const unsigned* _lp = (LP);                                                 \
  uint4 _xa0 = *(const uint4*)&XSH[0][(BASE)];                                \
  uint4 _xa1 = *(const uint4*)&XSH[0][(BASE) + 4];                            \
  uint4 _xb0 = *(const uint4*)&XSH[1][(BASE)];                                \
  uint4 _xb1 = *(const uint4*)&XSH[1][(BASE) + 4];                            \
  A0 = dot2f(_lp[0*(LS)], _xa0.x, A0); A0 = dot2f(_lp[1*(LS)], _xa0.y, A0);   \
  A0 = dot2f(_lp[2*(LS)], _xa0.z, A0); A0 = dot2f(_lp[3*(LS)], _xa0.w, A0);   \
  A0 = dot2f(_lp[4*(LS)], _xa1.x, A0); A0 = dot2f(_lp[5*(LS)], _xa1.y, A0);   \
  A0 = dot2f(_lp[6*(LS)], _xa1.z, A0); A0 = dot2f(_lp[7*(LS)], _xa1.w, A0);   \
  A1 = dot2f(_lp[0*(LS)], _xb0.x, A1); A1 = dot2f(_lp[1*(LS)], _xb0.y, A1);   \
  A1 = dot2f(_lp[2*(LS)], _xb0.z, A1); A1 = dot2f(_lp[3*(LS)], _xb0.w, A1);   \
  A1 = dot2f(_lp[4*(LS)], _xb1.x, A1); A1 = dot2f(_lp[5*(LS)], _xb1.y, A1);   \
  A1 = dot2f(_lp[6*(LS)], _xb1.z, A1); A1 = dot2f(_lp[7*(LS)], _xb1.w, A1);   \
} while (0)

// 24-kpair matmul, weights in LDS at stride LS
#define MM24L(LP, LS, XSH, BASE, A0, A1) do {                                  \
  const unsigned* _gp = (LP);                                                  \
  _Pragma("unroll")                                                            \
  for (int g = 0; g < 6; ++g) {                                                \
    uint4 xa = *(const uint4*)&XSH[0][(BASE) + g * 4];                         \
    uint4 xb = *(const uint4*)&XSH[1][(BASE) + g * 4];                         \
    A0 = dot2f(_gp[(g*4+0)*(LS)], xa.x, A0); A0 = dot2f(_gp[(g*4+1)*(LS)], xa.y, A0); \
    A0 = dot2f(_gp[(g*4+2)*(LS)], xa.z, A0); A0 = dot2f(_gp[(g*4+3)*(LS)], xa.w, A0); \
    A1 = dot2f(_gp[(g*4+0)*(LS)], xb.x, A1); A1 = dot2f(_gp[(g*4+1)*(LS)], xb.y, A1); \
    A1 = dot2f(_gp[(g*4+2)*(LS)], xb.z, A1); A1 = dot2f(_gp[(g*4+3)*(LS)], xb.w, A1); \
  }                                                                            \
} while (0)

// ---------------------------------------------------------------------------
// fold kernel: region-dispatch by blockIdx.x (874 blocks x 256 threads)
// ---------------------------------------------------------------------------
__global__ __launch_bounds__(256) void fold_k(
    const float* __restrict__ emb,  const float* __restrict__ selW,
    const float* __restrict__ selb, const float* __restrict__ PV,
    const float* __restrict__ bW1,  const float* __restrict__ bb1,
    const float* __restrict__ bW2,  const float* __restrict__ phE,
    const float* __restrict__ rW,   const float* __restrict__ sW1,
    const float* __restrict__ sW2,  const float* __restrict__ gW1,
    const float* __restrict__ decW, float* __restrict__ ws)
{
  unsigned* wsu = (unsigned*)ws;
  int blk = blockIdx.x, tid = threadIdx.x;

  if (blk < 64) {                       // sel_tok [256][64] f32
    int o = blk * 256 + tid; int v = o >> 6, c = o & 63;
    float a = selb[c];
    const float* er = emb + v * HD;
    for (int h = 0; h < HD; ++h) a += er[h] * selW[h * PSL + c];
    ws[OFF_SELTOK + o] = a;
  } else if (blk < 256) {               // bind_tok [256][192] f32
    int o = (blk - 64) * 256 + tid; int v = o / HD, c = o % HD;
    float a = bb1[c];
    const float* er = emb + v * HD;
    for (int h = 0; h < HD; ++h) a += er[h] * bW1[h * HD + c];
    ws[OFF_BINDTOK + o] = a;
  } else if (blk < 280) {               // PB2: PV @ bind_W1[192:384] (row-major)
    int o = (blk - 256) * 256 + tid; int k2 = o / HD, c = o % HD;
    float lo = 0.f, hi = 0.f;
    const float* p0 = PV + (2 * k2) * HD; const float* p1 = p0 + HD;
    for (int h = 0; h < HD; ++h) { float wv = bW1[(HD + h) * HD + c]; lo += p0[h] * wv; hi += p1[h] * wv; }
    wsu[OFF_PB + o] = pk2(lo, hi);
  } else if (blk < 304) {               // PS2: PV @ succ_W1[192:384]
    int o = (blk - 280) * 256 + tid; int k2 = o / HD, c = o % HD;
    float lo = 0.f, hi = 0.f;
    const float* p0 = PV + (2 * k2) * HD; const float* p1 = p0 + HD;
    for (int h = 0; h < HD; ++h) { float wv = sW1[(HD + h) * HD + c]; lo += p0[h] * wv; hi += p1[h] * wv; }
    wsu[OFF_PS + o] = pk2(lo, hi);
  } else if (blk < 310) {               // PhS2: phase_embed @ succ_W1[384:576]
    int o = (blk - 304) * 256 + tid; int k2 = o / HD, c = o % HD;
    float lo = 0.f, hi = 0.f;
    const float* p0 = phE + (2 * k2) * HD; const float* p1 = p0 + HD;
    for (int h = 0; h < HD; ++h) { float wv = sW1[(2 * HD + h) * HD + c]; lo += p0[h] * wv; hi += p1[h] * wv; }
    wsu[OFF_PHS + o] = pk2(lo, hi);
  } else if (blk < 334) {               // selWp2 [96][64]
    int o = (blk - 310) * 256 + tid; int k2 = o >> 6, c = o & 63;
    wsu[OFF_SELWP + o] = pk2(selW[(HD + 2 * k2) * PSL + c], selW[(HD + 2 * k2 + 1) * PSL + c]);
  } else if (blk < 406) {               // bindWp RE-LAID [(ms*192+mc)*24+i]
    int o = (blk - 334) * 256 + tid;
    int i = o % 24, q = o / 24;
    int mcol = q % HD, msl = q / HD;
    int j = msl * 24 + i;              // prev kpair index 0..95
    wsu[OFF_BINDWP + o] = pk2(bW1[(2 * HD + 2 * j) * HD + mcol],
                              bW1[(2 * HD + 2 * j + 1) * HD + mcol]);
  } else if (blk < 478) {               // bindW2p [96][192]
    int o = (blk - 406) * 256 + tid; int k2 = o / HD, c = o % HD;
    wsu[OFF_BINDW2 + o] = pk2(bW2[(2 * k2) * HD + c], bW2[(2 * k2 + 1) * HD + c]);
  } else if (blk < 490) {               // routerW2 [192][16]
    int o = (blk - 478) * 256 + tid; int k2 = o >> 4, c = o & 15;
    wsu[OFF_ROUTERW + o] = pk2(rW[(2 * k2) * PHD + c], rW[(2 * k2 + 1) * PHD + c]);
  } else if (blk < 562) {               // succWs2 [96][192]
    int o = (blk - 490) * 256 + tid; int k2 = o / HD, c = o % HD;
    wsu[OFF_SUCCWS + o] = pk2(sW1[(2 * k2) * HD + c], sW1[(2 * k2 + 1) * HD + c]);
  } else if (blk < 634) {               // succW2p [96][192]
    int o = (blk - 562) * 256 + tid; int k2 = o / HD, c = o % HD;
    wsu[OFF_SUCCW2 + o] = pk2(sW2[(2 * k2) * HD + c], sW2[(2 * k2 + 1) * HD + c]);
  } else if (blk < 706) {               // gateW1 sec-half row-major [96][192]
    int o = (blk - 634) * 256 + tid; int j = o / HD, c = o % HD;
    wsu[OFF_GATEW1 + o] = pk2(gW1[(2 * j) * HD + c], gW1[(2 * j + 1) * HD + c]);
  } else if (blk < 778) {               // gateW1 prev-half RE-LAID
    int o = (blk - 706) * 256 + tid;
    int i = o % 24, q = o / 24;
    int mcol = q % HD, msl = q / HD;
    int j = msl * 24 + i;              // prev kpair 0..95 -> gW1 rows 192+2j
    wsu[OFF_GATEW1 + 18432 + o] = pk2(gW1[(2 * (96 + j)) * HD + mcol],
                                      gW1[(2 * (96 + j) + 1) * HD + mcol]);
  } else {                              // dec2 [96][256]
    int o = (blk - 778) * 256 + tid; int k2 = o >> 8, c = o & 255;
    wsu[OFF_DEC + o] = pk2(decW[(2 * k2) * VOC + c], decW[(2 * k2 + 1) * VOC + c]);
  }
}

// ---------------------------------------------------------------------------
// rnn kernel: 256 blocks x 768 threads (12 waves, 3/SIMD), 2 rows per block
// ---------------------------------------------------------------------------
__global__ __launch_bounds__(768, 3) void rnn_k(
    const int* __restrict__ ids, const float* __restrict__ ws,
    const float* __restrict__ bind_b2, const float* __restrict__ router_b,
    const float* __restrict__ succ_b1, const float* __restrict__ succ_b2,
    const float* __restrict__ gate_b1, const float* __restrict__ gate_W2,
    const float* __restrict__ gate_b2, const float* __restrict__ ln_g,
    const float* __restrict__ ln_b,
    float* __restrict__ out_hidden, float* __restrict__ out_pw,
    float* __restrict__ out_phw, float* __restrict__ out_gate)
{
  const unsigned* wsu = (const unsigned*)ws;
  const float* sel_tok  = ws + OFF_SELTOK;
  const float* bind_tok = ws + OFF_BINDTOK;

  // LDS: weight slabs (staged once) + activation buffers; ~156.5 KB total
  __shared__ unsigned lds_gsec[96 * HD];   // 72 KB gateW1 sec-half row-major
  __shared__ unsigned lds_pb[32 * HD];     // 24 KB
  __shared__ unsigned lds_ps[32 * HD];     // 24 KB
  __shared__ unsigned lds_sel[96 * PSL];   // 24 KB
  __shared__ float    s_part[1536];
  __shared__ unsigned s_prevh[2][96], s_sech[2][96], s_xh[2][96], s_succh[2][96];
  __shared__ unsigned s_pwh[2][32];
  __shared__ unsigned s_phwh[2][8];
  __shared__ float    s_prev[2][HD], s_succ[2][HD];
  __shared__ int      s_tok[2];

  const int tid = threadIdx.x;
  const int u = tid >> 6, lane = tid & 63;
  const int b0 = blockIdx.x * 2;
  const int ms = u & 3, mc = ((u >> 2) << 6) + lane;   // matmul: k-slice x col
  const int rr = u & 1, rc = ((u >> 1) << 6) + lane;   // reduce: row x col
  const int sl5 = tid >> 4, c5 = tid & 15;             // router mapping

  // ---- stage LDS weight slabs ----
  for (int i = tid; i < 96 * HD; i += 768) lds_gsec[i] = wsu[OFF_GATEW1 + i];
  for (int i = tid; i < 32 * HD; i += 768) {
    lds_pb[i] = wsu[OFF_PB + i];
    lds_ps[i] = wsu[OFF_PS + i];
  }
  for (int i = tid; i < 96 * PSL; i += 768) lds_sel[i] = wsu[OFF_SELWP + i];

  // ---- register weight preloads (step-invariant) ----
  unsigned wRt[4], wB2[24], wSs[24], wS2[24], wPh[2];
#pragma unroll
  for (int i = 0; i < 4; ++i)  wRt[i] = wsu[OFF_ROUTERW + (sl5 * 4 + i) * PHD + c5];
#pragma unroll
  for (int i = 0; i < 24; ++i) wB2[i] = wsu[OFF_BINDW2 + (ms * 24 + i) * HD + mc];
#pragma unroll
  for (int i = 0; i < 24; ++i) wSs[i] = wsu[OFF_SUCCWS + (ms * 24 + i) * HD + mc];
#pragma unroll
  for (int i = 0; i < 24; ++i) wS2[i] = wsu[OFF_SUCCW2 + (ms * 24 + i) * HD + mc];
#pragma unroll
  for (int i = 0; i < 2; ++i)  wPh[i] = wsu[OFF_PHS + (ms * 2 + i) * HD + mc];

  // streamed-slab base pointers (per-thread contiguous 96 B, uint4-aligned)
  const uint4* pBWp = (const uint4*)(wsu + OFF_BINDWP + (ms * HD + mc) * 24);
  const uint4* pGWp = (const uint4*)(wsu + OFF_GATEW1 + 18432 + (ms * HD + mc) * 24);

  float f_bb2 = 0.f, f_sb1 = 0.f, f_sb2 = 0.f;
  if (u < 6) { f_bb2 = bind_b2[rc]; f_sb1 = succ_b1[rc]; f_sb2 = succ_b2[rc]; }
  float f_rb = 0.f, gb1_0 = 0.f, gb1_1 = 0.f, gb1_2 = 0.f;
  float gw2_0 = 0.f, gw2_1 = 0.f, gw2_2 = 0.f, f_gb2 = 0.f;
  float lg0 = 0.f, lg1 = 0.f, lg2 = 0.f, lb0 = 0.f, lb1 = 0.f, lb2 = 0.f;
  if (u < 2) {
    if (lane < PHD) f_rb = router_b[lane];
    gb1_0 = gate_b1[lane]; gb1_1 = gate_b1[lane + 64]; gb1_2 = gate_b1[lane + 128];
    gw2_0 = gate_W2[lane]; gw2_1 = gate_W2[lane + 64]; gw2_2 = gate_W2[lane + 128];
    f_gb2 = gate_b2[0];
    lg0 = ln_g[lane]; lg1 = ln_g[lane + 64]; lg2 = ln_g[lane + 128];
    lb0 = ln_b[lane]; lb1 = ln_b[lane + 64]; lb2 = ln_b[lane + 128];
  }

  for (int i = tid; i < 2 * HD; i += 768) s_prev[i / HD][i % HD] = 0.f;
  for (int i = tid; i < 2 * 96; i += 768) s_prevh[i / 96][i % 96] = 0u;
  if (u < 2 && lane == 0) s_tok[u] = ids[(b0 + u) * S_LEN];
  __syncthreads();

  for (int t = 0; t < S_LEN; ++t) {
    // ---- phase A: stream-issue bindWp + token gathers + P1 (sel prev) ----
    uint4 st[6];
#pragma unroll
    for (int j = 0; j < 6; ++j) st[j] = pBWp[j];
    float g_sel  = (u < 2) ? sel_tok[s_tok[u] * PSL + lane] : 0.f;
    float g_bind = (u < 6) ? bind_tok[s_tok[rr] * HD + rc] : 0.f;
    {
      float a0 = 0.f, a1 = 0.f;
      MM8L((&lds_sel[(u * 8) * PSL + lane]), PSL, s_prevh, u * 8, a0, a1);
      s_part[u * 64 + lane] = a0;
      s_part[(12 + u) * 64 + lane] = a1;
    }
    __syncthreads();

    // ---- P2: sel softmax (wave u = row u) ----
    if (u < 2) {
      float a = g_sel;
#pragma unroll
      for (int s = 0; s < 12; ++s) a += s_part[(u * 12 + s) * 64 + lane];
      float mx = a;
#pragma unroll
      for (int m = 32; m; m >>= 1) mx = fmaxf(mx, __shfl_xor(mx, m));
      float e = expf(a - mx);
      float sm = e;
#pragma unroll
      for (int m = 32; m; m >>= 1) sm += __shfl_xor(sm, m);
      float pv = e / sm;
      out_pw[(size_t)((b0 + u) * S_LEN + t) * PSL + lane] = pv;
      float ov = __shfl_xor(pv, 1);
      if (!(lane & 1)) s_pwh[u][lane >> 1] = pk2(pv, ov);
    }
    __syncthreads();

    // ---- P3: bind1 partials (PB from LDS + bindWp stream) ----
    {
      float a0 = 0.f, a1 = 0.f;
      MM8L((&lds_pb[(ms * 8) * HD + mc]), HD, s_pwh, ms * 8, a0, a1);
      MM24ST(st, s_prevh, ms * 24, a0, a1);
      s_part[ms * HD + mc] = a0;
      s_part[(4 + ms) * HD + mc] = a1;
    }
    __syncthreads();
    // ---- P3b: reduce + tok-table + gelu + pack ----
    if (u < 6) {
      float v = g_bind;
#pragma unroll
      for (int s = 0; s < 4; ++s) v += s_part[((rr << 2) | s) * HD + rc];
      float g = geluf(v);
      float o = __shfl_xor(g, 1);
      if (!(lane & 1)) s_xh[rr][rc >> 1] = pk2(g, o);
    }
    __syncthreads();

    // ---- P4: bind2 partials (register weights) ----
    {
      float a0 = 0.f, a1 = 0.f;
      MM24(wB2, s_xh, ms * 24, a0, a1);
      s_part[ms * HD + mc] = a0;
      s_part[(4 + ms) * HD + mc] = a1;
    }
    __syncthreads();
    // ---- P4b: reduce + bias + tanh -> sec ----
    if (u < 6) {
      float v = f_bb2;
#pragma unroll
      for (int s = 0; s < 4; ++s) v += s_part[((rr << 2) | s) * HD + rc];
      float sv = tanhf(v);
      float o = __shfl_xor(sv, 1);
      if (!(lane & 1)) s_sech[rr][rc >> 1] = pk2(sv, o);
    }
    __syncthreads();

    // ---- P5: router partials (48 slices x 16 cols, all 768 threads) ----
    {
      const unsigned* x0;
      const unsigned* x1;
      if (sl5 < 24) { x0 = &s_sech[0][sl5 * 4];        x1 = &s_sech[1][sl5 * 4]; }
      else          { x0 = &s_prevh[0][(sl5 - 24) * 4]; x1 = &s_prevh[1][(sl5 - 24) * 4]; }
      uint4 xa = *(const uint4*)x0, xb = *(const uint4*)x1;
      float a0 = 0.f, a1 = 0.f;
      a0 = dot2f(wRt[0], xa.x, a0); a0 = dot2f(wRt[1], xa.y, a0);
      a0 = dot2f(wRt[2], xa.z, a0); a0 = dot2f(wRt[3], xa.w, a0);
      a1 = dot2f(wRt[0], xb.x, a1); a1 = dot2f(wRt[1], xb.y, a1);
      a1 = dot2f(wRt[2], xb.z, a1); a1 = dot2f(wRt[3], xb.w, a1);
      s_part[sl5 * 16 + c5] = a0;
      s_part[768 + sl5 * 16 + c5] = a1;
    }
    __syncthreads();

    // ---- P6: router softmax (waves 0,1; lanes 0..15) ----
    if (u < 2 && lane < PHD) {
      float a = f_rb;
#pragma unroll
      for (int s = 0; s < 48; ++s) a += s_part[u * 768 + s * 16 + lane];
      float mx = a;
#pragma unroll
      for (int m = 8; m; m >>= 1) mx = fmaxf(mx, __shfl_xor(mx, m));
      float e = expf(a - mx);
      float sm = e;
#pragma unroll
      for (int m = 8; m; m >>= 1) sm += __shfl_xor(sm, m);
      float ph = e / sm;
      out_phw[(size_t)((b0 + u) * S_LEN + t) * PHD + lane] = ph;
      float ov = __shfl_xor(ph, 1);
      if (!(lane & 1)) s_phwh[u][lane >> 1] = pk2(ph, ov);
    }
    __syncthreads();

    // ---- P7: succ1 partials (succWs regs + PS LDS + PhS regs) ----
    {
      float a0 = 0.f, a1 = 0.f;
      MM24(wSs, s_sech, ms * 24, a0, a1);
      MM8L((&lds_ps[(ms * 8) * HD + mc]), HD, s_pwh, ms * 8, a0, a1);
      uint2 pa = *(const uint2*)&s_phwh[0][ms * 2];
      uint2 pb = *(const uint2*)&s_phwh[1][ms * 2];
      a0 = dot2f(wPh[0], pa.x, a0); a0 = dot2f(wPh[1], pa.y, a0);
      a1 = dot2f(wPh[0], pb.x, a1); a1 = dot2f(wPh[1], pb.y, a1);
      s_part[ms * HD + mc] = a0;
      s_part[(4 + ms) * HD + mc] = a1;
    }
    __syncthreads();
    // ---- P7b: reduce + bias + gelu + pack ----
    if (u < 6) {
      float v = f_sb1;
#pragma unroll
      for (int s = 0; s < 4; ++s) v += s_part[((rr << 2) | s) * HD + rc];
      float g = geluf(v);
      float o = __shfl_xor(g, 1);
      if (!(lane & 1)) s_xh[rr][rc >> 1] = pk2(g, o);
    }
    __syncthreads();

    // ---- P8: succ2 partials (register weights); issue gateW1-prev stream ----
    uint4 st9[6];
#pragma unroll
    for (int j = 0; j < 6; ++j) st9[j] = pGWp[j];
    {
      float a0 = 0.f, a1 = 0.f;
      MM24(wS2, s_xh, ms * 24, a0, a1);
      s_part[ms * HD + mc] = a0;
      s_part[(4 + ms) * HD + mc] = a1;
    }
    __syncthreads();
    // ---- P8b: reduce + bias + tanh -> succ (f32 + packed) ----
    if (u < 6) {
      float v = f_sb2;
#pragma unroll
      for (int s = 0; s < 4; ++s) v += s_part[((rr << 2) | s) * HD + rc];
      float sv = tanhf(v);
      s_succ[rr][rc] = sv;
      float o = __shfl_xor(sv, 1);
      if (!(lane & 1)) s_succh[rr][rc >> 1] = pk2(sv, o);
    }
    __syncthreads();

    // ---- P9: gate1 partials (gateW1-sec LDS + gateW1-prev stream) ----
    {
      float a0 = 0.f, a1 = 0.f;
      MM24L((&lds_gsec[(ms * 24) * HD + mc]), HD, s_succh, ms * 24, a0, a1);
      MM24ST(st9, s_prevh, ms * 24, a0, a1);
      s_part[ms * HD + mc] = a0;
      s_part[(4 + ms) * HD + mc] = a1;
    }
    __syncthreads();

    // ---- P10: gate reduce + blend + LayerNorm (waves 0,1) ----
    if (u < 2) {
      int c0 = lane, c1 = lane + 64, c2 = lane + 128;
      float v0 = gb1_0, v1 = gb1_1, v2 = gb1_2;
#pragma unroll
      for (int s = 0; s < 4; ++s) {
        v0 += s_part[((u << 2) | s) * HD + c0];
        v1 += s_part[((u << 2) | s) * HD + c1];
        v2 += s_part[((u << 2) | s) * HD + c2];
      }
      float gp = geluf(v0) * gw2_0 + geluf(v1) * gw2_1 + geluf(v2) * gw2_2;
#pragma unroll
      for (int m = 32; m; m >>= 1) gp += __shfl_xor(gp, m);
      float gv = 1.f / (1.f + expf(-(gp + f_gb2)));
      if (lane == 0) out_gate[(size_t)(b0 + u) * S_LEN + t] = gv;

      float h0 = gv * s_succ[u][c0] + (1.f - gv) * s_prev[u][c0];
      float h1 = gv * s_succ[u][c1] + (1.f - gv) * s_prev[u][c1];
      float h2v = gv * s_succ[u][c2] + (1.f - gv) * s_prev[u][c2];
      float sum = h0 + h1 + h2v;
#pragma unroll
      for (int m = 32; m; m >>= 1) sum += __shfl_xor(sum, m);
      float mean = sum * (1.f / 192.f);
      float d0 = h0 - mean, d1 = h1 - mean, d2 = h2v - mean;
      float vs = d0 * d0 + d1 * d1 + d2 * d2;
#pragma unroll
      for (int m = 32; m; m >>= 1) vs += __shfl_xor(vs, m);
      float rstd = rsqrtf(vs * (1.f / 192.f) + 1e-5f);
      float y0 = d0 * rstd * lg0 + lb0;
      float y1 = d1 * rstd * lg1 + lb1;
      float y2 = d2 * rstd * lg2 + lb2;
      size_t ho = (size_t)((b0 + u) * S_LEN + t) * HD;
      out_hidden[ho + c0] = y0;
      out_hidden[ho + c1] = y1;
      out_hidden[ho + c2] = y2;
      s_prev[u][c0] = y0; s_prev[u][c1] = y1; s_prev[u][c2] = y2;
      float o0 = __shfl_xor(y0, 1), o1 = __shfl_xor(y1, 1), o2 = __shfl_xor(y2, 1);
      if (!(lane & 1)) {
        s_prevh[u][c0 >> 1] = pk2(y0, o0);
        s_prevh[u][c1 >> 1] = pk2(y1, o1);
        s_prevh[u][c2 >> 1] = pk2(y2, o2);
      }
      if (lane == 0) s_tok[u] = ids[(b0 + u) * S_LEN + (t < S_LEN - 1 ? t + 1 : t)];
    }
    __syncthreads();
  }
}

// ---------------------------------------------------------------------------
// dec kernel: logits[65536,256] = hidden[65536,192] @ dec_W[192,256]
// ---------------------------------------------------------------------------
__global__ __launch_bounds__(256) void dec_k(
    const float* __restrict__ hid, const unsigned* __restrict__ dec2,
    float* __restrict__ logits)
{
  __shared__ __align__(16) unsigned sA[64][96];
  int tid = threadIdx.x;
  size_t r0 = (size_t)blockIdx.x * 64;

#pragma unroll
  for (int i = 0; i < 24; ++i) {
    int idx = i * 256 + tid;
    int rr = idx / 96, kk = idx % 96;
    const float2* hp = (const float2*)(hid + (r0 + rr) * HD);
    float2 v = hp[kk];
    sA[rr][kk] = pk2(v.x, v.y);
  }
  __syncthreads();

  int c = tid;
  unsigned wr[96];
#pragma unroll
  for (int k = 0; k < 96; ++k) wr[k] = dec2[k * VOC + c];

  for (int rr = 0; rr < 64; ++rr) {
    float acc = 0.f;
#pragma unroll
    for (int k4 = 0; k4 < 24; ++k4) {
      uint4 xv = *reinterpret_cast<const uint4*>(&sA[rr][k4 * 4]);
      acc = dot2f(wr[4 * k4 + 0], xv.x, acc);
      acc = dot2f(wr[4 * k4 + 1], xv.y, acc);
      acc = dot2f(wr[4 * k4 + 2], xv.z, acc);
      acc = dot2f(wr[4 * k4 + 3], xv.w, acc);
    }
    logits[(r0 + rr) * VOC + c] = acc;
  }
}

// ---------------------------------------------------------------------------
extern "C" void kernel_launch(void* const* d_in, const int* in_sizes, int n_in,
                              void* d_out, int out_size, void* d_ws, size_t ws_size,
                              hipStream_t stream)
{
  const int*   ids  = (const int*)d_in[0];
  const float* emb  = (const float*)d_in[1];
  const float* selW = (const float*)d_in[2];
  const float* selb = (const float*)d_in[3];
  const float* PV   = (const float*)d_in[4];
  const float* bW1  = (const float*)d_in[5];
  const float* bb1  = (const float*)d_in[6];
  const float* bW2  = (const float*)d_in[7];
  const float* bb2  = (const float*)d_in[8];
  const float* phE  = (const float*)d_in[9];
  const float* rW   = (const float*)d_in[10];
  const float* rb   = (const float*)d_in[11];
  const float* sW1  = (const float*)d_in[12];
  const float* sb1  = (const float*)d_in[13];
  const float* sW2  = (const float*)d_in[14];
  const float* sb2  = (const float*)d_in[15];
  const float* gW1  = (const float*)d_in[16];
  const float* gb1  = (const float*)d_in[17];
  const float* gW2  = (const float*)d_in[18];
  const float* gb2  = (const float*)d_in[19];
  const float* lng  = (const float*)d_in[20];
  const float* lnb  = (const float*)d_in[21];
  const float* decW = (const float*)d_in[22];

  float* out = (float*)d_out;
  float* o_logits = out;                         // [512][128][256]
  float* o_hidden = out + 16777216;              // [512][128][192]
  float* o_pw     = out + 29360128;              // [512][128][64]
  float* o_phw    = out + 33554432;              // [512][128][16]
  float* o_gate   = out + 34603008;              // [512][128][1]

  float* ws = (float*)d_ws;

  hipLaunchKernelGGL(fold_k, dim3(874), dim3(256), 0, stream,
                     emb, selW, selb, PV, bW1, bb1, bW2, phE, rW, sW1, sW2, gW1, decW, ws);
  hipLaunchKernelGGL(rnn_k, dim3(256), dim3(768), 0, stream,
                     ids, ws, bb2, rb, sb1, sb2, gb1, gW2, gb2, lng, lnb,
                     o_hidden, o_pw, o_phw, o_gate);
  hipLaunchKernelGGL(dec_k, dim3(1024), dim3(256), 0, stream,
                     o_hidden, ((const unsigned*)d_ws) + OFF_DEC, o_logits);
}